// Round 4
// baseline (735.441 us; speedup 1.0000x reference)
//
#include <hip/hip_runtime.h>
#include <hip/hip_bf16.h>
#include <cstdint>
#include <cstddef>

#define NROWS 16384
#define DDIM  256
#define SPLITS 24                 // 64 row-blocks x 24 col-splits = 1536 blocks = 6/CU
#define NTILES 256                // 16384 cols / 64

typedef __attribute__((ext_vector_type(4))) float f32x4;
typedef __attribute__((ext_vector_type(4))) float fl4;
typedef __attribute__((ext_vector_type(4))) int   i32x4;
typedef __attribute__((ext_vector_type(8))) int   i32x8;

constexpr float SCALE_EXP2 = 20.609929155556627f; // log2(e)/0.07 folded into qn
constexpr float LN2F       = 0.69314718055994531f;
constexpr float INV_T      = 14.285714285714286f;

__device__ inline void gload_lds16(const void* g, void* l) {
  __builtin_amdgcn_global_load_lds(
      (const __attribute__((address_space(1))) void*)g,
      (__attribute__((address_space(3))) void*)l, 16, 0, 0);
}

// ---- kernel 1: one wave per row i: normalize q_i,k_i -> fp8 (q side pre-scaled
// by log2(e)/T), fp32 diag_i, zero rowsum. No LDS, no barriers.
__global__ __launch_bounds__(256) void norm_kernel(
    const float* __restrict__ q, const float* __restrict__ k,
    unsigned char* __restrict__ qn, unsigned char* __restrict__ kn,
    float* __restrict__ diag, float* __restrict__ rowsum,
    float* __restrict__ out)
{
  const int wave = threadIdx.x >> 6, lane = threadIdx.x & 63;
  const int row = blockIdx.x * 4 + wave;
  const size_t off = (size_t)row * DDIM + lane * 4;

  fl4 vq = *(const fl4*)(q + off);
  fl4 vk = *(const fl4*)(k + off);
  float ssq = vq.x * vq.x + vq.y * vq.y + vq.z * vq.z + vq.w * vq.w;
  float ssk = vk.x * vk.x + vk.y * vk.y + vk.z * vk.z + vk.w * vk.w;
  float dot = vq.x * vk.x + vq.y * vk.y + vq.z * vk.z + vq.w * vk.w;
#pragma unroll
  for (int m = 1; m < 64; m <<= 1) {
    ssq += __shfl_xor(ssq, m, 64);
    ssk += __shfl_xor(ssk, m, 64);
    dot += __shfl_xor(dot, m, 64);
  }
  float rq = 1.0f / fmaxf(sqrtf(ssq), 1e-12f);
  float rk = 1.0f / fmaxf(sqrtf(ssk), 1e-12f);

  float sq = rq * SCALE_EXP2;   // fold exp2 scale into q side
  int pq = __builtin_amdgcn_cvt_pk_fp8_f32(vq.x * sq, vq.y * sq, 0, false);
  pq     = __builtin_amdgcn_cvt_pk_fp8_f32(vq.z * sq, vq.w * sq, pq, true);
  *(int*)(qn + off) = pq;
  int pk = __builtin_amdgcn_cvt_pk_fp8_f32(vk.x * rk, vk.y * rk, 0, false);
  pk     = __builtin_amdgcn_cvt_pk_fp8_f32(vk.z * rk, vk.w * rk, pk, true);
  *(int*)(kn + off) = pk;

  if (lane == 0) {
    diag[row]   = dot * rq * rk * INV_T;
    rowsum[row] = 0.0f;
    if (row == 0) out[0] = 0.0f;
  }
}

// ---- kernel 2: rowsum[row] += sum over this split's col-tiles of exp2(qn.kn)
// grid 1536 = 64 row-blocks x 24 splits. 4 waves x 64 rows. MX-fp8 K=128 MFMA.
// VGPR cap 102 (measured need: 84) -> 6 blocks/CU resident, 96 KB LDS total.
__global__ __launch_bounds__(256, 5) void lse_kernel(
    const unsigned char* __restrict__ qn, const unsigned char* __restrict__ kn,
    float* __restrict__ rowsum)
{
  __shared__ __attribute__((aligned(16))) unsigned char Bs[64 * DDIM]; // 16 KB

  const int tid  = threadIdx.x;
  const int wave = tid >> 6, lane = tid & 63;
  const int l15  = lane & 15, quad = lane >> 4;
  const int split = blockIdx.x % SPLITS;
  const int rb    = blockIdx.x / SPLITS;
  const int wrow  = rb * 256 + wave * 64;
  const int t0 = (split * NTILES) / SPLITS;
  const int t1 = ((split + 1) * NTILES) / SPLITS;

  // A fragments: 4 subtiles x 2 K-steps(128) x 32B/lane = 64 VGPRs.
  // Layout (16x16x128 f8f6f4): m = lane&15, k = quad*32 + j.
  i32x8 A[4][2];
#pragma unroll
  for (int s = 0; s < 4; ++s) {
    const unsigned char* ap = qn + (size_t)(wrow + s * 16 + l15) * DDIM + quad * 32;
#pragma unroll
    for (int ks = 0; ks < 2; ++ks)
      A[s][ks] = *(const i32x8*)(ap + ks * 128);
  }

  float sums[4][4];
#pragma unroll
  for (int s = 0; s < 4; ++s)
#pragma unroll
    for (int r = 0; r < 4; ++r) sums[s][r] = 0.0f;

  for (int ct = t0; ct < t1; ++ct) {
    const unsigned char* kbase = kn + (size_t)ct * 64 * DDIM;
    __syncthreads();
    // Stage 64 cols x 256B = 1024 16B chunks; slot jj of row n holds global
    // chunk j = jj ^ (n&15). LDS dest linear in tid (uniform base + lane*16).
#pragma unroll
    for (int i = 0; i < 4; ++i) {
      int L = i * 256 + tid;
      int n = L >> 4, jj = L & 15;
      int j = jj ^ (n & 15);
      gload_lds16(kbase + (size_t)n * DDIM + j * 16, (void*)(Bs + L * 16));
    }
    __syncthreads();

#pragma unroll
    for (int cs = 0; cs < 4; ++cs) {
      int n  = cs * 16 + l15;
      int nb = n & 15;
      const unsigned char* brow = Bs + n * DDIM;
      f32x4 acc0 = {0.f, 0.f, 0.f, 0.f};
      f32x4 acc1 = {0.f, 0.f, 0.f, 0.f};
      f32x4 acc2 = {0.f, 0.f, 0.f, 0.f};
      f32x4 acc3 = {0.f, 0.f, 0.f, 0.f};
#pragma unroll
      for (int ks = 0; ks < 2; ++ks) {
        int c0 = ks * 8 + quad * 2;
        i32x4 lo = *(const i32x4*)(brow + ((c0 ^ nb) * 16));
        i32x4 hi = *(const i32x4*)(brow + (((c0 + 1) ^ nb) * 16));
        i32x8 b = {lo.x, lo.y, lo.z, lo.w, hi.x, hi.y, hi.z, hi.w};
        acc0 = __builtin_amdgcn_mfma_scale_f32_16x16x128_f8f6f4(A[0][ks], b, acc0, 0, 0, 0, 127, 0, 127);
        acc1 = __builtin_amdgcn_mfma_scale_f32_16x16x128_f8f6f4(A[1][ks], b, acc1, 0, 0, 0, 127, 0, 127);
        acc2 = __builtin_amdgcn_mfma_scale_f32_16x16x128_f8f6f4(A[2][ks], b, acc2, 0, 0, 0, 127, 0, 127);
        acc3 = __builtin_amdgcn_mfma_scale_f32_16x16x128_f8f6f4(A[3][ks], b, acc3, 0, 0, 0, 127, 0, 127);
      }
      // C/D: col = lane&15, row = quad*4 + r. qn pre-scaled -> exp2 directly.
#pragma unroll
      for (int r = 0; r < 4; ++r) {
        sums[0][r] += __builtin_amdgcn_exp2f(acc0[r]);
        sums[1][r] += __builtin_amdgcn_exp2f(acc1[r]);
        sums[2][r] += __builtin_amdgcn_exp2f(acc2[r]);
        sums[3][r] += __builtin_amdgcn_exp2f(acc3[r]);
      }
    }
  }

#pragma unroll
  for (int s = 0; s < 4; ++s)
#pragma unroll
    for (int r = 0; r < 4; ++r) {
      float v = sums[s][r];
      v += __shfl_xor(v, 1, 64);
      v += __shfl_xor(v, 2, 64);
      v += __shfl_xor(v, 4, 64);
      v += __shfl_xor(v, 8, 64);
      if (l15 == 0) atomicAdd(&rowsum[wrow + s * 16 + quad * 4 + r], v);
    }
}

// ---- kernel 3: out = mean(ln(rowsum) - diag)
__global__ void final_kernel(const float* __restrict__ rowsum,
                             const float* __restrict__ diag,
                             float* __restrict__ out)
{
  int row = blockIdx.x * 256 + threadIdx.x;
  float c = __builtin_amdgcn_logf(rowsum[row]) * LN2F - diag[row];
#pragma unroll
  for (int m = 1; m < 64; m <<= 1) c += __shfl_xor(c, m, 64);
  __shared__ float red[4];
  int wave = threadIdx.x >> 6, lane = threadIdx.x & 63;
  if (lane == 0) red[wave] = c;
  __syncthreads();
  if (threadIdx.x == 0) {
    float s = red[0] + red[1] + red[2] + red[3];
    atomicAdd(out, s * (1.0f / NROWS));
  }
}

extern "C" void kernel_launch(void* const* d_in, const int* in_sizes, int n_in,
                              void* d_out, int out_size, void* d_ws, size_t ws_size,
                              hipStream_t stream)
{
  const float* q = (const float*)d_in[0];
  const float* k = (const float*)d_in[1];
  float* out = (float*)d_out;

  char* ws = (char*)d_ws;
  unsigned char* qn = (unsigned char*)ws;                    // 4 MB
  unsigned char* kn = (unsigned char*)(ws + (4u << 20));     // 4 MB
  float* diag   = (float*)(ws + (8u << 20));                 // 64 KB
  float* rowsum = (float*)(ws + (8u << 20) + (64u << 10));   // 64 KB

  norm_kernel <<<NROWS / 4, 256, 0, stream>>>(q, k, qn, kn, diag, rowsum, out);
  lse_kernel  <<<(NROWS / 256) * SPLITS, 256, 0, stream>>>(qn, kn, rowsum);
  final_kernel<<<NROWS / 256, 256, 0, stream>>>(rowsum, diag, out);
}

// Round 5
// 186.950 us; speedup vs baseline: 3.9339x; 3.9339x over previous
//
#include <hip/hip_runtime.h>
#include <hip/hip_bf16.h>
#include <cstdint>
#include <cstddef>

#define NROWS 16384
#define DDIM  256
#define SPLITS 24                 // 64 row-blocks x 24 col-splits = 1536 blocks = 6/CU
#define NTILES 256                // 16384 cols / 64

typedef __attribute__((ext_vector_type(4))) float f32x4;
typedef __attribute__((ext_vector_type(4))) float fl4;
typedef __attribute__((ext_vector_type(4))) int   i32x4;
typedef __attribute__((ext_vector_type(8))) int   i32x8;

constexpr float SCALE_EXP2 = 20.609929155556627f; // log2(e)/0.07 folded into qn
constexpr float LN2F       = 0.69314718055994531f;
constexpr float INV_T      = 14.285714285714286f;

__device__ inline void gload_lds16(const void* g, void* l) {
  __builtin_amdgcn_global_load_lds(
      (const __attribute__((address_space(1))) void*)g,
      (__attribute__((address_space(3))) void*)l, 16, 0, 0);
}

// ---- kernel 1: one wave per row i: normalize q_i,k_i -> fp8 (q side pre-scaled
// by log2(e)/T), fp32 diag_i, zero rowsum. No LDS, no barriers.
__global__ __launch_bounds__(256) void norm_kernel(
    const float* __restrict__ q, const float* __restrict__ k,
    unsigned char* __restrict__ qn, unsigned char* __restrict__ kn,
    float* __restrict__ diag, float* __restrict__ rowsum,
    float* __restrict__ out)
{
  const int wave = threadIdx.x >> 6, lane = threadIdx.x & 63;
  const int row = blockIdx.x * 4 + wave;
  const size_t off = (size_t)row * DDIM + lane * 4;

  fl4 vq = *(const fl4*)(q + off);
  fl4 vk = *(const fl4*)(k + off);
  float ssq = vq.x * vq.x + vq.y * vq.y + vq.z * vq.z + vq.w * vq.w;
  float ssk = vk.x * vk.x + vk.y * vk.y + vk.z * vk.z + vk.w * vk.w;
  float dot = vq.x * vk.x + vq.y * vk.y + vq.z * vk.z + vq.w * vk.w;
#pragma unroll
  for (int m = 1; m < 64; m <<= 1) {
    ssq += __shfl_xor(ssq, m, 64);
    ssk += __shfl_xor(ssk, m, 64);
    dot += __shfl_xor(dot, m, 64);
  }
  float rq = 1.0f / fmaxf(sqrtf(ssq), 1e-12f);
  float rk = 1.0f / fmaxf(sqrtf(ssk), 1e-12f);

  float sq = rq * SCALE_EXP2;   // fold exp2 scale into q side
  int pq = __builtin_amdgcn_cvt_pk_fp8_f32(vq.x * sq, vq.y * sq, 0, false);
  pq     = __builtin_amdgcn_cvt_pk_fp8_f32(vq.z * sq, vq.w * sq, pq, true);
  *(int*)(qn + off) = pq;
  int pk = __builtin_amdgcn_cvt_pk_fp8_f32(vk.x * rk, vk.y * rk, 0, false);
  pk     = __builtin_amdgcn_cvt_pk_fp8_f32(vk.z * rk, vk.w * rk, pk, true);
  *(int*)(kn + off) = pk;

  if (lane == 0) {
    diag[row]   = dot * rq * rk * INV_T;
    rowsum[row] = 0.0f;
    if (row == 0) out[0] = 0.0f;
  }
}

// ---- kernel 2: rowsum[row] += sum over this split's col-tiles of exp2(qn.kn)
// grid 1536 = 64 row-blocks x 24 splits. 4 waves x 64 rows. MX-fp8 K=128 MFMA.
// launch_bounds(256,3): proven binary (84 VGPR, no spill) -> 512/84 = 6 waves/SIMD
// = 6 blocks/CU residency set by the GRID, not the bound. (256,5) spilled (R4).
__global__ __launch_bounds__(256, 3) void lse_kernel(
    const unsigned char* __restrict__ qn, const unsigned char* __restrict__ kn,
    float* __restrict__ rowsum)
{
  __shared__ __attribute__((aligned(16))) unsigned char Bs[64 * DDIM]; // 16 KB

  const int tid  = threadIdx.x;
  const int wave = tid >> 6, lane = tid & 63;
  const int l15  = lane & 15, quad = lane >> 4;
  const int split = blockIdx.x % SPLITS;
  const int rb    = blockIdx.x / SPLITS;
  const int wrow  = rb * 256 + wave * 64;
  const int t0 = (split * NTILES) / SPLITS;
  const int t1 = ((split + 1) * NTILES) / SPLITS;

  // A fragments: 4 subtiles x 2 K-steps(128) x 32B/lane = 64 VGPRs.
  // Layout (16x16x128 f8f6f4): m = lane&15, k = quad*32 + j.
  i32x8 A[4][2];
#pragma unroll
  for (int s = 0; s < 4; ++s) {
    const unsigned char* ap = qn + (size_t)(wrow + s * 16 + l15) * DDIM + quad * 32;
#pragma unroll
    for (int ks = 0; ks < 2; ++ks)
      A[s][ks] = *(const i32x8*)(ap + ks * 128);
  }

  float sums[4][4];
#pragma unroll
  for (int s = 0; s < 4; ++s)
#pragma unroll
    for (int r = 0; r < 4; ++r) sums[s][r] = 0.0f;

  for (int ct = t0; ct < t1; ++ct) {
    const unsigned char* kbase = kn + (size_t)ct * 64 * DDIM;
    __syncthreads();
    // Stage 64 cols x 256B = 1024 16B chunks; slot jj of row n holds global
    // chunk j = jj ^ (n&15). LDS dest linear in tid (uniform base + lane*16).
#pragma unroll
    for (int i = 0; i < 4; ++i) {
      int L = i * 256 + tid;
      int n = L >> 4, jj = L & 15;
      int j = jj ^ (n & 15);
      gload_lds16(kbase + (size_t)n * DDIM + j * 16, (void*)(Bs + L * 16));
    }
    __syncthreads();

#pragma unroll
    for (int cs = 0; cs < 4; ++cs) {
      int n  = cs * 16 + l15;
      int nb = n & 15;
      const unsigned char* brow = Bs + n * DDIM;
      f32x4 acc0 = {0.f, 0.f, 0.f, 0.f};
      f32x4 acc1 = {0.f, 0.f, 0.f, 0.f};
      f32x4 acc2 = {0.f, 0.f, 0.f, 0.f};
      f32x4 acc3 = {0.f, 0.f, 0.f, 0.f};
#pragma unroll
      for (int ks = 0; ks < 2; ++ks) {
        int c0 = ks * 8 + quad * 2;
        i32x4 lo = *(const i32x4*)(brow + ((c0 ^ nb) * 16));
        i32x4 hi = *(const i32x4*)(brow + (((c0 + 1) ^ nb) * 16));
        i32x8 b = {lo.x, lo.y, lo.z, lo.w, hi.x, hi.y, hi.z, hi.w};
        acc0 = __builtin_amdgcn_mfma_scale_f32_16x16x128_f8f6f4(A[0][ks], b, acc0, 0, 0, 0, 127, 0, 127);
        acc1 = __builtin_amdgcn_mfma_scale_f32_16x16x128_f8f6f4(A[1][ks], b, acc1, 0, 0, 0, 127, 0, 127);
        acc2 = __builtin_amdgcn_mfma_scale_f32_16x16x128_f8f6f4(A[2][ks], b, acc2, 0, 0, 0, 127, 0, 127);
        acc3 = __builtin_amdgcn_mfma_scale_f32_16x16x128_f8f6f4(A[3][ks], b, acc3, 0, 0, 0, 127, 0, 127);
      }
      // C/D: col = lane&15, row = quad*4 + r. qn pre-scaled -> exp2 directly.
#pragma unroll
      for (int r = 0; r < 4; ++r) {
        sums[0][r] += __builtin_amdgcn_exp2f(acc0[r]);
        sums[1][r] += __builtin_amdgcn_exp2f(acc1[r]);
        sums[2][r] += __builtin_amdgcn_exp2f(acc2[r]);
        sums[3][r] += __builtin_amdgcn_exp2f(acc3[r]);
      }
    }
  }

#pragma unroll
  for (int s = 0; s < 4; ++s)
#pragma unroll
    for (int r = 0; r < 4; ++r) {
      float v = sums[s][r];
      v += __shfl_xor(v, 1, 64);
      v += __shfl_xor(v, 2, 64);
      v += __shfl_xor(v, 4, 64);
      v += __shfl_xor(v, 8, 64);
      if (l15 == 0) atomicAdd(&rowsum[wrow + s * 16 + quad * 4 + r], v);
    }
}

// ---- kernel 3: out = mean(ln(rowsum) - diag)
__global__ void final_kernel(const float* __restrict__ rowsum,
                             const float* __restrict__ diag,
                             float* __restrict__ out)
{
  int row = blockIdx.x * 256 + threadIdx.x;
  float c = __builtin_amdgcn_logf(rowsum[row]) * LN2F - diag[row];
#pragma unroll
  for (int m = 1; m < 64; m <<= 1) c += __shfl_xor(c, m, 64);
  __shared__ float red[4];
  int wave = threadIdx.x >> 6, lane = threadIdx.x & 63;
  if (lane == 0) red[wave] = c;
  __syncthreads();
  if (threadIdx.x == 0) {
    float s = red[0] + red[1] + red[2] + red[3];
    atomicAdd(out, s * (1.0f / NROWS));
  }
}

extern "C" void kernel_launch(void* const* d_in, const int* in_sizes, int n_in,
                              void* d_out, int out_size, void* d_ws, size_t ws_size,
                              hipStream_t stream)
{
  const float* q = (const float*)d_in[0];
  const float* k = (const float*)d_in[1];
  float* out = (float*)d_out;

  char* ws = (char*)d_ws;
  unsigned char* qn = (unsigned char*)ws;                    // 4 MB
  unsigned char* kn = (unsigned char*)(ws + (4u << 20));     // 4 MB
  float* diag   = (float*)(ws + (8u << 20));                 // 64 KB
  float* rowsum = (float*)(ws + (8u << 20) + (64u << 10));   // 64 KB

  norm_kernel <<<NROWS / 4, 256, 0, stream>>>(q, k, qn, kn, diag, rowsum, out);
  lse_kernel  <<<(NROWS / 256) * SPLITS, 256, 0, stream>>>(qn, kn, rowsum);
  final_kernel<<<NROWS / 256, 256, 0, stream>>>(rowsum, diag, out);
}

// Round 7
// 151.330 us; speedup vs baseline: 4.8598x; 1.2354x over previous
//
#include <hip/hip_runtime.h>
#include <hip/hip_bf16.h>
#include <cstdint>
#include <cstddef>

#define NROWS 16384
#define DDIM  256
#define SPLITS 12                 // 64 row-blocks x 12 col-splits = 768 blocks = 3/CU
#define NTILES 256                // 16384 cols / 64

typedef __attribute__((ext_vector_type(4))) float f32x4;
typedef __attribute__((ext_vector_type(4))) float fl4;
typedef __attribute__((ext_vector_type(4))) int   i32x4;
typedef __attribute__((ext_vector_type(8))) int   i32x8;

constexpr float SCALE_EXP2 = 20.609929155556627f; // log2(e)/0.07 folded into qn
constexpr float LN2F       = 0.69314718055994531f;
constexpr float INV_T      = 14.285714285714286f;

__device__ inline void gload_lds16(const void* g, void* l) {
  __builtin_amdgcn_global_load_lds(
      (const __attribute__((address_space(1))) void*)g,
      (__attribute__((address_space(3))) void*)l, 16, 0, 0);
}

// ---- kernel 1: one wave per row i: normalize q_i,k_i -> fp8 (q side pre-scaled
// by log2(e)/T), fp32 diag_i, zero rowsum. No LDS, no barriers.
__global__ __launch_bounds__(256) void norm_kernel(
    const float* __restrict__ q, const float* __restrict__ k,
    unsigned char* __restrict__ qn, unsigned char* __restrict__ kn,
    float* __restrict__ diag, float* __restrict__ rowsum,
    float* __restrict__ out)
{
  const int wave = threadIdx.x >> 6, lane = threadIdx.x & 63;
  const int row = blockIdx.x * 4 + wave;
  const size_t off = (size_t)row * DDIM + lane * 4;

  fl4 vq = *(const fl4*)(q + off);
  fl4 vk = *(const fl4*)(k + off);
  float ssq = vq.x * vq.x + vq.y * vq.y + vq.z * vq.z + vq.w * vq.w;
  float ssk = vk.x * vk.x + vk.y * vk.y + vk.z * vk.z + vk.w * vk.w;
  float dot = vq.x * vk.x + vq.y * vk.y + vq.z * vk.z + vq.w * vk.w;
#pragma unroll
  for (int m = 1; m < 64; m <<= 1) {
    ssq += __shfl_xor(ssq, m, 64);
    ssk += __shfl_xor(ssk, m, 64);
    dot += __shfl_xor(dot, m, 64);
  }
  float rq = 1.0f / fmaxf(sqrtf(ssq), 1e-12f);
  float rk = 1.0f / fmaxf(sqrtf(ssk), 1e-12f);

  float sq = rq * SCALE_EXP2;   // fold exp2 scale into q side
  int pq = __builtin_amdgcn_cvt_pk_fp8_f32(vq.x * sq, vq.y * sq, 0, false);
  pq     = __builtin_amdgcn_cvt_pk_fp8_f32(vq.z * sq, vq.w * sq, pq, true);
  *(int*)(qn + off) = pq;
  int pk = __builtin_amdgcn_cvt_pk_fp8_f32(vk.x * rk, vk.y * rk, 0, false);
  pk     = __builtin_amdgcn_cvt_pk_fp8_f32(vk.z * rk, vk.w * rk, pk, true);
  *(int*)(kn + off) = pk;

  if (lane == 0) {
    diag[row]   = dot * rq * rk * INV_T;
    rowsum[row] = 0.0f;
    if (row == 0) out[0] = 0.0f;
  }
}

// ---- kernel 2: rowsum[row] += sum over this split's col-tiles of exp2(qn.kn)
// grid 768 = 64 row-blocks x 12 splits. 4 waves x 64 rows. MX-fp8 K=128 MFMA.
// __launch_bounds__(256) ONLY (no min-waves): with (256,3) the unified file
// split 84 arch / 84 acc and the 64-reg A-hoard spilled to scratch every tile
// (R5: 133 MB WRITE_SIZE, MfmaUtil 23%). Unconstrained, the allocator keeps A
// resident (~130-170 arch VGPRs -> still 3 waves/SIMD = grid residency).
// Proven single-buffer two-barrier staging (R3/R5-correct); no post-barrier
// prefetch (R6's dbuf raced LDS-DMA vs barrier -> NaN).
__global__ __launch_bounds__(256) void lse_kernel(
    const unsigned char* __restrict__ qn, const unsigned char* __restrict__ kn,
    float* __restrict__ rowsum)
{
  __shared__ __attribute__((aligned(16))) unsigned char Bs[64 * DDIM]; // 16 KB

  const int tid  = threadIdx.x;
  const int wave = tid >> 6, lane = tid & 63;
  const int l15  = lane & 15, quad = lane >> 4;
  const int split = blockIdx.x % SPLITS;
  const int rb    = blockIdx.x / SPLITS;
  const int wrow  = rb * 256 + wave * 64;
  const int t0 = (split * NTILES) / SPLITS;
  const int t1 = ((split + 1) * NTILES) / SPLITS;

  // A fragments: 4 subtiles x 2 K-steps(128) x 32B/lane = 64 VGPRs.
  // Layout (16x16x128 f8f6f4): m = lane&15, k = quad*32 + j.
  i32x8 A[4][2];
#pragma unroll
  for (int s = 0; s < 4; ++s) {
    const unsigned char* ap = qn + (size_t)(wrow + s * 16 + l15) * DDIM + quad * 32;
#pragma unroll
    for (int ks = 0; ks < 2; ++ks)
      A[s][ks] = *(const i32x8*)(ap + ks * 128);
  }

  float sums[4][4];
#pragma unroll
  for (int s = 0; s < 4; ++s)
#pragma unroll
    for (int r = 0; r < 4; ++r) sums[s][r] = 0.0f;

  for (int ct = t0; ct < t1; ++ct) {
    const unsigned char* kbase = kn + (size_t)ct * 64 * DDIM;
    __syncthreads();
    // Stage 64 cols x 256B = 1024 16B chunks; slot jj of row n holds global
    // chunk j = jj ^ (n&15). LDS dest linear in tid (uniform base + lane*16).
#pragma unroll
    for (int i = 0; i < 4; ++i) {
      int L = i * 256 + tid;
      int n = L >> 4, jj = L & 15;
      int j = jj ^ (n & 15);
      gload_lds16(kbase + (size_t)n * DDIM + j * 16, (void*)(Bs + L * 16));
    }
    __syncthreads();

#pragma unroll
    for (int cs = 0; cs < 4; ++cs) {
      int n  = cs * 16 + l15;
      int nb = n & 15;
      const unsigned char* brow = Bs + n * DDIM;
      f32x4 acc0 = {0.f, 0.f, 0.f, 0.f};
      f32x4 acc1 = {0.f, 0.f, 0.f, 0.f};
      f32x4 acc2 = {0.f, 0.f, 0.f, 0.f};
      f32x4 acc3 = {0.f, 0.f, 0.f, 0.f};
#pragma unroll
      for (int ks = 0; ks < 2; ++ks) {
        int c0 = ks * 8 + quad * 2;
        i32x4 lo = *(const i32x4*)(brow + ((c0 ^ nb) * 16));
        i32x4 hi = *(const i32x4*)(brow + (((c0 + 1) ^ nb) * 16));
        i32x8 b = {lo.x, lo.y, lo.z, lo.w, hi.x, hi.y, hi.z, hi.w};
        acc0 = __builtin_amdgcn_mfma_scale_f32_16x16x128_f8f6f4(A[0][ks], b, acc0, 0, 0, 0, 127, 0, 127);
        acc1 = __builtin_amdgcn_mfma_scale_f32_16x16x128_f8f6f4(A[1][ks], b, acc1, 0, 0, 0, 127, 0, 127);
        acc2 = __builtin_amdgcn_mfma_scale_f32_16x16x128_f8f6f4(A[2][ks], b, acc2, 0, 0, 0, 127, 0, 127);
        acc3 = __builtin_amdgcn_mfma_scale_f32_16x16x128_f8f6f4(A[3][ks], b, acc3, 0, 0, 0, 127, 0, 127);
      }
      // C/D: col = lane&15, row = quad*4 + r. qn pre-scaled -> exp2 directly.
#pragma unroll
      for (int r = 0; r < 4; ++r) {
        sums[0][r] += __builtin_amdgcn_exp2f(acc0[r]);
        sums[1][r] += __builtin_amdgcn_exp2f(acc1[r]);
        sums[2][r] += __builtin_amdgcn_exp2f(acc2[r]);
        sums[3][r] += __builtin_amdgcn_exp2f(acc3[r]);
      }
    }
  }

#pragma unroll
  for (int s = 0; s < 4; ++s)
#pragma unroll
    for (int r = 0; r < 4; ++r) {
      float v = sums[s][r];
      v += __shfl_xor(v, 1, 64);
      v += __shfl_xor(v, 2, 64);
      v += __shfl_xor(v, 4, 64);
      v += __shfl_xor(v, 8, 64);
      if (l15 == 0) atomicAdd(&rowsum[wrow + s * 16 + quad * 4 + r], v);
    }
}

// ---- kernel 3: out = mean(ln(rowsum) - diag)
__global__ void final_kernel(const float* __restrict__ rowsum,
                             const float* __restrict__ diag,
                             float* __restrict__ out)
{
  int row = blockIdx.x * 256 + threadIdx.x;
  float c = __builtin_amdgcn_logf(rowsum[row]) * LN2F - diag[row];
#pragma unroll
  for (int m = 1; m < 64; m <<= 1) c += __shfl_xor(c, m, 64);
  __shared__ float red[4];
  int wave = threadIdx.x >> 6, lane = threadIdx.x & 63;
  if (lane == 0) red[wave] = c;
  __syncthreads();
  if (threadIdx.x == 0) {
    float s = red[0] + red[1] + red[2] + red[3];
    atomicAdd(out, s * (1.0f / NROWS));
  }
}

extern "C" void kernel_launch(void* const* d_in, const int* in_sizes, int n_in,
                              void* d_out, int out_size, void* d_ws, size_t ws_size,
                              hipStream_t stream)
{
  const float* q = (const float*)d_in[0];
  const float* k = (const float*)d_in[1];
  float* out = (float*)d_out;

  char* ws = (char*)d_ws;
  unsigned char* qn = (unsigned char*)ws;                    // 4 MB
  unsigned char* kn = (unsigned char*)(ws + (4u << 20));     // 4 MB
  float* diag   = (float*)(ws + (8u << 20));                 // 64 KB
  float* rowsum = (float*)(ws + (8u << 20) + (64u << 10));   // 64 KB

  norm_kernel <<<NROWS / 4, 256, 0, stream>>>(q, k, qn, kn, diag, rowsum, out);
  lse_kernel  <<<(NROWS / 256) * SPLITS, 256, 0, stream>>>(qn, kn, rowsum);
  final_kernel<<<NROWS / 256, 256, 0, stream>>>(rowsum, diag, out);
}

// Round 8
// 148.337 us; speedup vs baseline: 4.9579x; 1.0202x over previous
//
#include <hip/hip_runtime.h>
#include <hip/hip_bf16.h>
#include <cstdint>
#include <cstddef>

#define NROWS 16384
#define DDIM  256
#define SPLITS 16                 // 64 row-blocks x 16 col-splits = 1024 blocks = 4/CU
#define NTILES 256                // 16384 cols / 64

typedef __attribute__((ext_vector_type(4))) float f32x4;
typedef __attribute__((ext_vector_type(4))) float fl4;
typedef __attribute__((ext_vector_type(4))) int   i32x4;
typedef __attribute__((ext_vector_type(8))) int   i32x8;

constexpr float SCALE_EXP2 = 20.609929155556627f; // log2(e)/0.07 folded into qn
constexpr float LN2F       = 0.69314718055994531f;
constexpr float INV_T      = 14.285714285714286f;

__device__ inline void gload_lds16(const void* g, void* l) {
  __builtin_amdgcn_global_load_lds(
      (const __attribute__((address_space(1))) void*)g,
      (__attribute__((address_space(3))) void*)l, 16, 0, 0);
}

// ---- kernel 1: one wave per row i: normalize q_i,k_i -> fp8 (q side pre-scaled
// by log2(e)/T), fp32 diag_i, zero rowsum. No LDS, no barriers.
__global__ __launch_bounds__(256) void norm_kernel(
    const float* __restrict__ q, const float* __restrict__ k,
    unsigned char* __restrict__ qn, unsigned char* __restrict__ kn,
    float* __restrict__ diag, float* __restrict__ rowsum,
    float* __restrict__ out)
{
  const int wave = threadIdx.x >> 6, lane = threadIdx.x & 63;
  const int row = blockIdx.x * 4 + wave;
  const size_t off = (size_t)row * DDIM + lane * 4;

  fl4 vq = *(const fl4*)(q + off);
  fl4 vk = *(const fl4*)(k + off);
  float ssq = vq.x * vq.x + vq.y * vq.y + vq.z * vq.z + vq.w * vq.w;
  float ssk = vk.x * vk.x + vk.y * vk.y + vk.z * vk.z + vk.w * vk.w;
  float dot = vq.x * vk.x + vq.y * vk.y + vq.z * vk.z + vq.w * vk.w;
#pragma unroll
  for (int m = 1; m < 64; m <<= 1) {
    ssq += __shfl_xor(ssq, m, 64);
    ssk += __shfl_xor(ssk, m, 64);
    dot += __shfl_xor(dot, m, 64);
  }
  float rq = 1.0f / fmaxf(sqrtf(ssq), 1e-12f);
  float rk = 1.0f / fmaxf(sqrtf(ssk), 1e-12f);

  float sq = rq * SCALE_EXP2;   // fold exp2 scale into q side
  int pq = __builtin_amdgcn_cvt_pk_fp8_f32(vq.x * sq, vq.y * sq, 0, false);
  pq     = __builtin_amdgcn_cvt_pk_fp8_f32(vq.z * sq, vq.w * sq, pq, true);
  *(int*)(qn + off) = pq;
  int pk = __builtin_amdgcn_cvt_pk_fp8_f32(vk.x * rk, vk.y * rk, 0, false);
  pk     = __builtin_amdgcn_cvt_pk_fp8_f32(vk.z * rk, vk.w * rk, pk, true);
  *(int*)(kn + off) = pk;

  if (lane == 0) {
    diag[row]   = dot * rq * rk * INV_T;
    rowsum[row] = 0.0f;
    if (row == 0) out[0] = 0.0f;
  }
}

// ---- kernel 2: rowsum[row] += sum over this split's col-tiles of exp2(qn.kn)
// grid 1024 = 64 row-blocks x 16 splits -> 4 blocks/CU = 4 waves/SIMD
// (VGPR 116 x 4 = 464 <= 512; LDS 4 x 16 KB = 64 KB). R7 showed MFMA and VALU
// serializing with only 3 waves/SIMD; the 4th independent wave is the overlap
// lever. __launch_bounds__(256) ONLY — (256,3+) splits the unified file and
// spills the A-hoard (R4/R5: 133MB-1GB scratch traffic).
__global__ __launch_bounds__(256) void lse_kernel(
    const unsigned char* __restrict__ qn, const unsigned char* __restrict__ kn,
    float* __restrict__ rowsum)
{
  __shared__ __attribute__((aligned(16))) unsigned char Bs[64 * DDIM]; // 16 KB

  const int tid  = threadIdx.x;
  const int wave = tid >> 6, lane = tid & 63;
  const int l15  = lane & 15, quad = lane >> 4;
  const int split = blockIdx.x % SPLITS;
  const int rb    = blockIdx.x / SPLITS;
  const int wrow  = rb * 256 + wave * 64;
  const int t0 = (split * NTILES) / SPLITS;
  const int t1 = ((split + 1) * NTILES) / SPLITS;

  // A fragments: 4 subtiles x 2 K-steps(128) x 32B/lane = 64 VGPRs.
  // Layout (16x16x128 f8f6f4): m = lane&15, k = quad*32 + j.
  i32x8 A[4][2];
#pragma unroll
  for (int s = 0; s < 4; ++s) {
    const unsigned char* ap = qn + (size_t)(wrow + s * 16 + l15) * DDIM + quad * 32;
#pragma unroll
    for (int ks = 0; ks < 2; ++ks)
      A[s][ks] = *(const i32x8*)(ap + ks * 128);
  }

  float sums[4][4];
#pragma unroll
  for (int s = 0; s < 4; ++s)
#pragma unroll
    for (int r = 0; r < 4; ++r) sums[s][r] = 0.0f;

  for (int ct = t0; ct < t1; ++ct) {
    const unsigned char* kbase = kn + (size_t)ct * 64 * DDIM;
    __syncthreads();
    // Stage 64 cols x 256B = 1024 16B chunks; slot jj of row n holds global
    // chunk j = jj ^ (n&15). LDS dest linear in tid (uniform base + lane*16).
#pragma unroll
    for (int i = 0; i < 4; ++i) {
      int L = i * 256 + tid;
      int n = L >> 4, jj = L & 15;
      int j = jj ^ (n & 15);
      gload_lds16(kbase + (size_t)n * DDIM + j * 16, (void*)(Bs + L * 16));
    }
    __syncthreads();

#pragma unroll
    for (int cs = 0; cs < 4; ++cs) {
      int n  = cs * 16 + l15;
      int nb = n & 15;
      const unsigned char* brow = Bs + n * DDIM;
      f32x4 acc0 = {0.f, 0.f, 0.f, 0.f};
      f32x4 acc1 = {0.f, 0.f, 0.f, 0.f};
      f32x4 acc2 = {0.f, 0.f, 0.f, 0.f};
      f32x4 acc3 = {0.f, 0.f, 0.f, 0.f};
#pragma unroll
      for (int ks = 0; ks < 2; ++ks) {
        int c0 = ks * 8 + quad * 2;
        i32x4 lo = *(const i32x4*)(brow + ((c0 ^ nb) * 16));
        i32x4 hi = *(const i32x4*)(brow + (((c0 + 1) ^ nb) * 16));
        i32x8 b = {lo.x, lo.y, lo.z, lo.w, hi.x, hi.y, hi.z, hi.w};
        acc0 = __builtin_amdgcn_mfma_scale_f32_16x16x128_f8f6f4(A[0][ks], b, acc0, 0, 0, 0, 127, 0, 127);
        acc1 = __builtin_amdgcn_mfma_scale_f32_16x16x128_f8f6f4(A[1][ks], b, acc1, 0, 0, 0, 127, 0, 127);
        acc2 = __builtin_amdgcn_mfma_scale_f32_16x16x128_f8f6f4(A[2][ks], b, acc2, 0, 0, 0, 127, 0, 127);
        acc3 = __builtin_amdgcn_mfma_scale_f32_16x16x128_f8f6f4(A[3][ks], b, acc3, 0, 0, 0, 127, 0, 127);
      }
      // C/D: col = lane&15, row = quad*4 + r. qn pre-scaled -> exp2 directly.
#pragma unroll
      for (int r = 0; r < 4; ++r) {
        sums[0][r] += __builtin_amdgcn_exp2f(acc0[r]);
        sums[1][r] += __builtin_amdgcn_exp2f(acc1[r]);
        sums[2][r] += __builtin_amdgcn_exp2f(acc2[r]);
        sums[3][r] += __builtin_amdgcn_exp2f(acc3[r]);
      }
    }
  }

#pragma unroll
  for (int s = 0; s < 4; ++s)
#pragma unroll
    for (int r = 0; r < 4; ++r) {
      float v = sums[s][r];
      v += __shfl_xor(v, 1, 64);
      v += __shfl_xor(v, 2, 64);
      v += __shfl_xor(v, 4, 64);
      v += __shfl_xor(v, 8, 64);
      if (l15 == 0) atomicAdd(&rowsum[wrow + s * 16 + quad * 4 + r], v);
    }
}

// ---- kernel 3: out = mean(ln(rowsum) - diag)
__global__ void final_kernel(const float* __restrict__ rowsum,
                             const float* __restrict__ diag,
                             float* __restrict__ out)
{
  int row = blockIdx.x * 256 + threadIdx.x;
  float c = __builtin_amdgcn_logf(rowsum[row]) * LN2F - diag[row];
#pragma unroll
  for (int m = 1; m < 64; m <<= 1) c += __shfl_xor(c, m, 64);
  __shared__ float red[4];
  int wave = threadIdx.x >> 6, lane = threadIdx.x & 63;
  if (lane == 0) red[wave] = c;
  __syncthreads();
  if (threadIdx.x == 0) {
    float s = red[0] + red[1] + red[2] + red[3];
    atomicAdd(out, s * (1.0f / NROWS));
  }
}

extern "C" void kernel_launch(void* const* d_in, const int* in_sizes, int n_in,
                              void* d_out, int out_size, void* d_ws, size_t ws_size,
                              hipStream_t stream)
{
  const float* q = (const float*)d_in[0];
  const float* k = (const float*)d_in[1];
  float* out = (float*)d_out;

  char* ws = (char*)d_ws;
  unsigned char* qn = (unsigned char*)ws;                    // 4 MB
  unsigned char* kn = (unsigned char*)(ws + (4u << 20));     // 4 MB
  float* diag   = (float*)(ws + (8u << 20));                 // 64 KB
  float* rowsum = (float*)(ws + (8u << 20) + (64u << 10));   // 64 KB

  norm_kernel <<<NROWS / 4, 256, 0, stream>>>(q, k, qn, kn, diag, rowsum, out);
  lse_kernel  <<<(NROWS / 256) * SPLITS, 256, 0, stream>>>(qn, kn, rowsum);
  final_kernel<<<NROWS / 256, 256, 0, stream>>>(rowsum, diag, out);
}

// Round 9
// 140.935 us; speedup vs baseline: 5.2183x; 1.0525x over previous
//
#include <hip/hip_runtime.h>
#include <hip/hip_bf16.h>
#include <cstdint>
#include <cstddef>

#define NROWS 16384
#define DDIM  256
#define SPLITS 16                 // 64 row-blocks x 16 col-splits = 1024 blocks = 4/CU
#define NTILES 256                // 16384 cols / 64

typedef __attribute__((ext_vector_type(4))) float f32x4;
typedef __attribute__((ext_vector_type(4))) float fl4;
typedef __attribute__((ext_vector_type(4))) int   i32x4;
typedef __attribute__((ext_vector_type(8))) int   i32x8;

constexpr float SCALE_EXP2 = 20.609929155556627f; // log2(e)/0.07 folded into qn
constexpr float LN2F       = 0.69314718055994531f;
constexpr float INV_T      = 14.285714285714286f;

__device__ inline void gload_lds16(const void* g, void* l) {
  __builtin_amdgcn_global_load_lds(
      (const __attribute__((address_space(1))) void*)g,
      (__attribute__((address_space(3))) void*)l, 16, 0, 0);
}

// ---- kernel 1: one wave per row i: normalize q_i,k_i -> fp8 (q side pre-scaled
// by log2(e)/T), fp32 diag_i, zero rowsum. No LDS, no barriers.
__global__ __launch_bounds__(256) void norm_kernel(
    const float* __restrict__ q, const float* __restrict__ k,
    unsigned char* __restrict__ qn, unsigned char* __restrict__ kn,
    float* __restrict__ diag, float* __restrict__ rowsum,
    float* __restrict__ out)
{
  const int wave = threadIdx.x >> 6, lane = threadIdx.x & 63;
  const int row = blockIdx.x * 4 + wave;
  const size_t off = (size_t)row * DDIM + lane * 4;

  fl4 vq = *(const fl4*)(q + off);
  fl4 vk = *(const fl4*)(k + off);
  float ssq = vq.x * vq.x + vq.y * vq.y + vq.z * vq.z + vq.w * vq.w;
  float ssk = vk.x * vk.x + vk.y * vk.y + vk.z * vk.z + vk.w * vk.w;
  float dot = vq.x * vk.x + vq.y * vk.y + vq.z * vk.z + vq.w * vk.w;
#pragma unroll
  for (int m = 1; m < 64; m <<= 1) {
    ssq += __shfl_xor(ssq, m, 64);
    ssk += __shfl_xor(ssk, m, 64);
    dot += __shfl_xor(dot, m, 64);
  }
  float rq = 1.0f / fmaxf(sqrtf(ssq), 1e-12f);
  float rk = 1.0f / fmaxf(sqrtf(ssk), 1e-12f);

  float sq = rq * SCALE_EXP2;   // fold exp2 scale into q side
  int pq = __builtin_amdgcn_cvt_pk_fp8_f32(vq.x * sq, vq.y * sq, 0, false);
  pq     = __builtin_amdgcn_cvt_pk_fp8_f32(vq.z * sq, vq.w * sq, pq, true);
  *(int*)(qn + off) = pq;
  int pk = __builtin_amdgcn_cvt_pk_fp8_f32(vk.x * rk, vk.y * rk, 0, false);
  pk     = __builtin_amdgcn_cvt_pk_fp8_f32(vk.z * rk, vk.w * rk, pk, true);
  *(int*)(kn + off) = pk;

  if (lane == 0) {
    diag[row]   = dot * rq * rk * INV_T;
    rowsum[row] = 0.0f;
    if (row == 0) out[0] = 0.0f;
  }
}

// ---- kernel 2: rowsum[row] += sum over this split's col-tiles of exp2(qn.kn)
// grid 1024 = 64 row-blocks x 16 splits -> 4 blocks/CU = 4 waves/SIMD.
// Double-buffered LDS staging: prefetch tile t+1 AFTER the barrier, compute
// tile t while its loads fly. R8 measured ~800 cyc stall per staging round
// (loads issued between the two barriers -> full latency exposed).
// CRITICAL correctness note (R6 NaN post-mortem): the compiler does NOT drain
// LDS-DMA (global_load_lds, vmcnt) before s_barrier — an explicit
// s_waitcnt(0) before __syncthreads() is required so buf[cur]'s prefetch
// (issued last iteration) has landed.
// __launch_bounds__(256) ONLY — any min-waves arg splits the unified file and
// spills the A-hoard (R4/R5: 133MB-1GB scratch traffic).
__global__ __launch_bounds__(256) void lse_kernel(
    const unsigned char* __restrict__ qn, const unsigned char* __restrict__ kn,
    float* __restrict__ rowsum)
{
  __shared__ __attribute__((aligned(16))) unsigned char Bs[2][64 * DDIM]; // 2 x 16 KB

  const int tid  = threadIdx.x;
  const int wave = tid >> 6, lane = tid & 63;
  const int l15  = lane & 15, quad = lane >> 4;
  const int split = blockIdx.x % SPLITS;
  const int rb    = blockIdx.x / SPLITS;
  const int wrow  = rb * 256 + wave * 64;
  const int t0 = (split * NTILES) / SPLITS;
  const int t1 = ((split + 1) * NTILES) / SPLITS;

  // Staging addresses (i-invariant): chunk L = i*256+tid -> row n = i*16+Ln,
  // slot jj = tid&15 holds global chunk j = jj ^ (n&15) = Ljj ^ Ln.
  const int Ln = tid >> 4, Ljj = tid & 15;
  const int Lj = Ljj ^ Ln;
  const size_t src_off = (size_t)Ln * DDIM + (size_t)Lj * 16;

  // A fragments: 4 subtiles x 2 K-steps(128) x 32B/lane = 64 VGPRs.
  // Layout (16x16x128 f8f6f4): m = lane&15, k = quad*32 + j.
  i32x8 A[4][2];
#pragma unroll
  for (int s = 0; s < 4; ++s) {
    const unsigned char* ap = qn + (size_t)(wrow + s * 16 + l15) * DDIM + quad * 32;
#pragma unroll
    for (int ks = 0; ks < 2; ++ks)
      A[s][ks] = *(const i32x8*)(ap + ks * 128);
  }

  float sums[4][4];
#pragma unroll
  for (int s = 0; s < 4; ++s)
#pragma unroll
    for (int r = 0; r < 4; ++r) sums[s][r] = 0.0f;

  // prefetch first tile into buffer 0
  {
    const unsigned char* kbase = kn + (size_t)t0 * 64 * DDIM + src_off;
#pragma unroll
    for (int i = 0; i < 4; ++i)
      gload_lds16(kbase + i * 4096, (void*)(Bs[0] + tid * 16 + i * 4096));
  }

  for (int ct = t0; ct < t1; ++ct) {
    const int cur = (ct - t0) & 1;
    __builtin_amdgcn_s_waitcnt(0);  // drain buf[cur]'s LDS-DMA (compiler won't)
    __syncthreads();                // + all waves done reading buf[cur^1]
    if (ct + 1 < t1) {
      const unsigned char* kbase = kn + (size_t)(ct + 1) * 64 * DDIM + src_off;
#pragma unroll
      for (int i = 0; i < 4; ++i)
        gload_lds16(kbase + i * 4096, (void*)(Bs[cur ^ 1] + tid * 16 + i * 4096));
    }

#pragma unroll
    for (int cs = 0; cs < 4; ++cs) {
      int n  = cs * 16 + l15;
      int nb = n & 15;
      const unsigned char* brow = Bs[cur] + n * DDIM;
      f32x4 acc0 = {0.f, 0.f, 0.f, 0.f};
      f32x4 acc1 = {0.f, 0.f, 0.f, 0.f};
      f32x4 acc2 = {0.f, 0.f, 0.f, 0.f};
      f32x4 acc3 = {0.f, 0.f, 0.f, 0.f};
#pragma unroll
      for (int ks = 0; ks < 2; ++ks) {
        int c0 = ks * 8 + quad * 2;
        i32x4 lo = *(const i32x4*)(brow + ((c0 ^ nb) * 16));
        i32x4 hi = *(const i32x4*)(brow + (((c0 + 1) ^ nb) * 16));
        i32x8 b = {lo.x, lo.y, lo.z, lo.w, hi.x, hi.y, hi.z, hi.w};
        acc0 = __builtin_amdgcn_mfma_scale_f32_16x16x128_f8f6f4(A[0][ks], b, acc0, 0, 0, 0, 127, 0, 127);
        acc1 = __builtin_amdgcn_mfma_scale_f32_16x16x128_f8f6f4(A[1][ks], b, acc1, 0, 0, 0, 127, 0, 127);
        acc2 = __builtin_amdgcn_mfma_scale_f32_16x16x128_f8f6f4(A[2][ks], b, acc2, 0, 0, 0, 127, 0, 127);
        acc3 = __builtin_amdgcn_mfma_scale_f32_16x16x128_f8f6f4(A[3][ks], b, acc3, 0, 0, 0, 127, 0, 127);
      }
      // C/D: col = lane&15, row = quad*4 + r. qn pre-scaled -> exp2 directly.
#pragma unroll
      for (int r = 0; r < 4; ++r) {
        sums[0][r] += __builtin_amdgcn_exp2f(acc0[r]);
        sums[1][r] += __builtin_amdgcn_exp2f(acc1[r]);
        sums[2][r] += __builtin_amdgcn_exp2f(acc2[r]);
        sums[3][r] += __builtin_amdgcn_exp2f(acc3[r]);
      }
    }
  }

#pragma unroll
  for (int s = 0; s < 4; ++s)
#pragma unroll
    for (int r = 0; r < 4; ++r) {
      float v = sums[s][r];
      v += __shfl_xor(v, 1, 64);
      v += __shfl_xor(v, 2, 64);
      v += __shfl_xor(v, 4, 64);
      v += __shfl_xor(v, 8, 64);
      if (l15 == 0) atomicAdd(&rowsum[wrow + s * 16 + quad * 4 + r], v);
    }
}

// ---- kernel 3: out = mean(ln(rowsum) - diag)
__global__ void final_kernel(const float* __restrict__ rowsum,
                             const float* __restrict__ diag,
                             float* __restrict__ out)
{
  int row = blockIdx.x * 256 + threadIdx.x;
  float c = __builtin_amdgcn_logf(rowsum[row]) * LN2F - diag[row];
#pragma unroll
  for (int m = 1; m < 64; m <<= 1) c += __shfl_xor(c, m, 64);
  __shared__ float red[4];
  int wave = threadIdx.x >> 6, lane = threadIdx.x & 63;
  if (lane == 0) red[wave] = c;
  __syncthreads();
  if (threadIdx.x == 0) {
    float s = red[0] + red[1] + red[2] + red[3];
    atomicAdd(out, s * (1.0f / NROWS));
  }
}

extern "C" void kernel_launch(void* const* d_in, const int* in_sizes, int n_in,
                              void* d_out, int out_size, void* d_ws, size_t ws_size,
                              hipStream_t stream)
{
  const float* q = (const float*)d_in[0];
  const float* k = (const float*)d_in[1];
  float* out = (float*)d_out;

  char* ws = (char*)d_ws;
  unsigned char* qn = (unsigned char*)ws;                    // 4 MB
  unsigned char* kn = (unsigned char*)(ws + (4u << 20));     // 4 MB
  float* diag   = (float*)(ws + (8u << 20));                 // 64 KB
  float* rowsum = (float*)(ws + (8u << 20) + (64u << 10));   // 64 KB

  norm_kernel <<<NROWS / 4, 256, 0, stream>>>(q, k, qn, kn, diag, rowsum, out);
  lse_kernel  <<<(NROWS / 256) * SPLITS, 256, 0, stream>>>(qn, kn, rowsum);
  final_kernel<<<NROWS / 256, 256, 0, stream>>>(rowsum, diag, out);
}